// Round 1
// baseline (450.155 us; speedup 1.0000x reference)
//
#include <hip/hip_runtime.h>

constexpr int FD = 64;   // feature dim of both GCN layers (H == O == 64)

// ---------------- CSR build ----------------

__global__ void k_deg(const int* __restrict__ dst, int E, int* __restrict__ deg) {
    int i = blockIdx.x * blockDim.x + threadIdx.x;
    if (i < E) atomicAdd(&deg[dst[i]], 1);
}

// Block-level exclusive scan of 1024 elements (16 waves of 64). Writes
// per-element exclusive-within-block prefix to out, block total to partials.
// Safe for in-place (in == out) within a single block: all reads precede the
// first barrier, all writes follow the last barrier.
__global__ __launch_bounds__(1024) void k_scan_block(const int* __restrict__ in, int n,
                                                     int* __restrict__ out,
                                                     int* __restrict__ partials) {
    __shared__ int wsum[16];
    int gid  = blockIdx.x * 1024 + threadIdx.x;
    int lane = threadIdx.x & 63, wid = threadIdx.x >> 6;
    int v = (gid < n) ? in[gid] : 0;
    int x = v;
#pragma unroll
    for (int o = 1; o < 64; o <<= 1) { int y = __shfl_up(x, o, 64); if (lane >= o) x += y; }
    if (lane == 63) wsum[wid] = x;
    __syncthreads();
    if (wid == 0) {
        int s = (lane < 16) ? wsum[lane] : 0;
#pragma unroll
        for (int o = 1; o < 16; o <<= 1) { int y = __shfl_up(s, o, 64); if (lane >= o) s += y; }
        if (lane < 16) wsum[lane] = s;   // inclusive scan of wave sums
    }
    __syncthreads();
    int base = (wid > 0) ? wsum[wid - 1] : 0;
    int incl = base + x;
    if (gid < n) out[gid] = incl - v;                       // exclusive
    if (partials && threadIdx.x == 1023) partials[blockIdx.x] = incl;  // block total
}

__global__ void k_fix(int* __restrict__ rowptr, const int* __restrict__ partials,
                      const int* __restrict__ deg, float* __restrict__ dinv, int n, int E) {
    int i = blockIdx.x * blockDim.x + threadIdx.x;
    if (i < n) {
        rowptr[i] += partials[i >> 10];
        dinv[i] = rsqrtf((float)(deg[i] + 1));   // +1 = self-loop
    }
    if (i == 0) rowptr[n] = E;
}

__global__ void k_scatter(const int* __restrict__ src, const int* __restrict__ dst, int E,
                          const int* __restrict__ rowptr, int* __restrict__ cursor,
                          int* __restrict__ col) {
    int e = blockIdx.x * blockDim.x + threadIdx.x;
    if (e < E) {
        int d = dst[e];
        int pos = rowptr[d] + atomicAdd(&cursor[d], 1);
        col[pos] = src[e];
    }
}

// ---------------- dense GEMM: Y[n,64] = act(X)[n,K] @ W[K,64] ----------------

template <int K, bool RELU>
__global__ __launch_bounds__(256) void k_gemm(const float* __restrict__ X,
                                              const float* __restrict__ W,
                                              float* __restrict__ Y, int n) {
    __shared__ __align__(16) float Wl[K * FD];
    __shared__ __align__(16) float xr[4][K];
    for (int i = threadIdx.x; i < K * FD / 4; i += 256)
        ((float4*)Wl)[i] = ((const float4*)W)[i];
    __syncthreads();
    int wid = threadIdx.x >> 6, lane = threadIdx.x & 63;
    for (int base = blockIdx.x * 4; base < n; base += gridDim.x * 4) {
        int r = base + wid;
        if (r < n) {
#pragma unroll
            for (int i = lane; i < K; i += 64) {
                float v = X[(size_t)r * K + i];
                xr[wid][i] = RELU ? fmaxf(v, 0.f) : v;
            }
        }
        __syncthreads();
        if (r < n) {
            float a0 = 0, a1 = 0, a2 = 0, a3 = 0;
#pragma unroll
            for (int k = 0; k < K; k += 4) {
                float4 xv = *(const float4*)&xr[wid][k];
                a0 = fmaf(xv.x, Wl[(k + 0) * FD + lane], a0);
                a1 = fmaf(xv.y, Wl[(k + 1) * FD + lane], a1);
                a2 = fmaf(xv.z, Wl[(k + 2) * FD + lane], a2);
                a3 = fmaf(xv.w, Wl[(k + 3) * FD + lane], a3);
            }
            Y[(size_t)r * FD + lane] = (a0 + a1) + (a2 + a3);
        }
        __syncthreads();
    }
}

// ---------------- edge aggregation (CSR by dst, no atomics) ----------------
// out[d] = dinv[d] * sum_{e: dst=d} dinv[src_e] * X[src_e] + dinv[d]^2 * X[d] + bias

__global__ __launch_bounds__(256) void k_agg(const float* __restrict__ X,
                                             const int* __restrict__ col,
                                             const int* __restrict__ rowptr,
                                             const float* __restrict__ dinv,
                                             const float* __restrict__ bias,
                                             float* __restrict__ out, int n) {
    int t = blockIdx.x * 256 + threadIdx.x;
    int node = t >> 4;
    int lane = t & 15;
    if (node >= n) return;
    int beg = rowptr[node], end = rowptr[node + 1];
    float4 acc = make_float4(0.f, 0.f, 0.f, 0.f);
    for (int e = beg; e < end; ++e) {
        int s = col[e];
        float w = dinv[s];
        float4 v = ((const float4*)(X + (size_t)s * FD))[lane];
        acc.x = fmaf(w, v.x, acc.x);
        acc.y = fmaf(w, v.y, acc.y);
        acc.z = fmaf(w, v.z, acc.z);
        acc.w = fmaf(w, v.w, acc.w);
    }
    float di = dinv[node];
    float4 sv = ((const float4*)(X + (size_t)node * FD))[lane];
    float4 b  = ((const float4*)bias)[lane];
    float4 o;
    o.x = fmaf(di, acc.x, fmaf(di * di, sv.x, b.x));
    o.y = fmaf(di, acc.y, fmaf(di * di, sv.y, b.y));
    o.z = fmaf(di, acc.z, fmaf(di * di, sv.z, b.z));
    o.w = fmaf(di, acc.w, fmaf(di * di, sv.w, b.w));
    ((float4*)(out + (size_t)node * FD))[lane] = o;
}

// ---------------- launch ----------------

extern "C" void kernel_launch(void* const* d_in, const int* in_sizes, int n_in,
                              void* d_out, int out_size, void* d_ws, size_t ws_size,
                              hipStream_t stream) {
    const float* emb = (const float*)d_in[0];
    const float* W1  = (const float*)d_in[1];
    const float* b1  = (const float*)d_in[2];
    const float* W2  = (const float*)d_in[3];
    const float* b2  = (const float*)d_in[4];
    const int*   src = (const int*)d_in[5];
    const int*   dst = (const int*)d_in[6];

    const int D = 128;
    const int N = in_sizes[0] / D;
    const int E = in_sizes[5];
    float* out = (float*)d_out;

    // workspace layout (all 4B types; d_ws is 256B-aligned)
    float* A        = (float*)d_ws;                 // N*FD f32 scratch (xW1, then hW2)
    int*   col      = (int*)(A + (size_t)N * FD);   // E   CSR column (src ids)
    int*   deg      = col + E;                      // N
    int*   cursor   = deg + N;                      // N   (adjacent to deg for one memset)
    int*   rowptr   = cursor + N;                   // N+1
    int*   partials = rowptr + N + 1;               // <=1024
    float* dinv     = (float*)(partials + 1024);    // N

    hipMemsetAsync(deg, 0, sizeof(int) * (size_t)(2 * N), stream);  // deg + cursor

    int npart = (N + 1023) >> 10;
    k_deg<<<(E + 255) / 256, 256, 0, stream>>>(dst, E, deg);
    k_scan_block<<<npart, 1024, 0, stream>>>(deg, N, rowptr, partials);
    k_scan_block<<<1, 1024, 0, stream>>>(partials, npart, partials, nullptr);
    k_fix<<<(N + 255) / 256, 256, 0, stream>>>(rowptr, partials, deg, dinv, N, E);
    k_scatter<<<(E + 255) / 256, 256, 0, stream>>>(src, dst, E, rowptr, cursor, col);

    // layer 1: A = emb @ W1 ; out(h) = aggregate(A) + b1   (ReLU deferred to GEMM-2 load)
    k_gemm<128, false><<<4096, 256, 0, stream>>>(emb, W1, A, N);
    k_agg<<<(N * 16 + 255) / 256, 256, 0, stream>>>(A, col, rowptr, dinv, b1, out, N);
    // layer 2: A = relu(h) @ W2 ; out = aggregate(A) + b2
    k_gemm<64, true><<<4096, 256, 0, stream>>>(out, W2, A, N);
    k_agg<<<(N * 16 + 255) / 256, 256, 0, stream>>>(A, col, rowptr, dinv, b2, out, N);
}

// Round 2
// 419.175 us; speedup vs baseline: 1.0739x; 1.0739x over previous
//
#include <hip/hip_runtime.h>

constexpr int FD = 64;   // feature dim of both GCN layers (H == O == 64)
constexpr int P  = 8;    // dst-range partitions (== #XCDs; blockIdx%8 ~ XCD)

// ---------------- CSR build (XCD-partitioned to kill write amplification) ----

// Each partition p owns dst in [p*npp, (p+1)*npp). Blocks with blockIdx%P==p
// scan the whole edge stream (grid-strided among themselves) and only touch
// deg/cursor/col lines inside their partition -> lines live in one XCD's L2.
__global__ __launch_bounds__(256) void k_deg_part(const int* __restrict__ dst, int E,
                                                  int* __restrict__ deg,
                                                  int npp, int N) {
    int p  = blockIdx.x & (P - 1);
    int j  = blockIdx.x >> 3;
    int B  = gridDim.x >> 3;
    int lo = p * npp;
    int hi = min(lo + npp, N);
    for (int e = j * 256 + threadIdx.x; e < E; e += B * 256) {
        int d = dst[e];
        if (d >= lo && d < hi) atomicAdd(&deg[d], 1);
    }
}

__global__ __launch_bounds__(256) void k_scatter_part(const int* __restrict__ src,
                                                      const int* __restrict__ dst, int E,
                                                      const int* __restrict__ rowptr,
                                                      int* __restrict__ cursor,
                                                      int* __restrict__ col,
                                                      int npp, int N) {
    int p  = blockIdx.x & (P - 1);
    int j  = blockIdx.x >> 3;
    int B  = gridDim.x >> 3;
    int lo = p * npp;
    int hi = min(lo + npp, N);
    for (int e = j * 256 + threadIdx.x; e < E; e += B * 256) {
        int d = dst[e];
        if (d >= lo && d < hi) {
            int pos = rowptr[d] + atomicAdd(&cursor[d], 1);
            col[pos] = src[e];
        }
    }
}

// Block-level exclusive scan of 1024 elements (16 waves of 64).
__global__ __launch_bounds__(1024) void k_scan_block(const int* __restrict__ in, int n,
                                                     int* __restrict__ out,
                                                     int* __restrict__ partials) {
    __shared__ int wsum[16];
    int gid  = blockIdx.x * 1024 + threadIdx.x;
    int lane = threadIdx.x & 63, wid = threadIdx.x >> 6;
    int v = (gid < n) ? in[gid] : 0;
    int x = v;
#pragma unroll
    for (int o = 1; o < 64; o <<= 1) { int y = __shfl_up(x, o, 64); if (lane >= o) x += y; }
    if (lane == 63) wsum[wid] = x;
    __syncthreads();
    if (wid == 0) {
        int s = (lane < 16) ? wsum[lane] : 0;
#pragma unroll
        for (int o = 1; o < 16; o <<= 1) { int y = __shfl_up(s, o, 64); if (lane >= o) s += y; }
        if (lane < 16) wsum[lane] = s;   // inclusive scan of wave sums
    }
    __syncthreads();
    int base = (wid > 0) ? wsum[wid - 1] : 0;
    int incl = base + x;
    if (gid < n) out[gid] = incl - v;                       // exclusive
    if (partials && threadIdx.x == 1023) partials[blockIdx.x] = incl;  // block total
}

__global__ void k_fix(int* __restrict__ rowptr, const int* __restrict__ partials,
                      const int* __restrict__ deg, float* __restrict__ dinv, int n, int E) {
    int i = blockIdx.x * blockDim.x + threadIdx.x;
    if (i < n) {
        rowptr[i] += partials[i >> 10];
        dinv[i] = rsqrtf((float)(deg[i] + 1));   // +1 = self-loop
    }
    if (i == 0) rowptr[n] = E;
}

// ---------------- dense GEMM: Y[n,64] = act(X)[n,K] @ W[K,64] ----------------

template <int K, bool RELU>
__global__ __launch_bounds__(256) void k_gemm(const float* __restrict__ X,
                                              const float* __restrict__ W,
                                              float* __restrict__ Y, int n) {
    __shared__ __align__(16) float Wl[K * FD];
    __shared__ __align__(16) float xr[4][K];
    for (int i = threadIdx.x; i < K * FD / 4; i += 256)
        ((float4*)Wl)[i] = ((const float4*)W)[i];
    __syncthreads();
    int wid = threadIdx.x >> 6, lane = threadIdx.x & 63;
    for (int base = blockIdx.x * 4; base < n; base += gridDim.x * 4) {
        int r = base + wid;
        if (r < n) {
#pragma unroll
            for (int i = lane; i < K; i += 64) {
                float v = X[(size_t)r * K + i];
                xr[wid][i] = RELU ? fmaxf(v, 0.f) : v;
            }
        }
        __syncthreads();
        if (r < n) {
            float a0 = 0, a1 = 0, a2 = 0, a3 = 0;
#pragma unroll
            for (int k = 0; k < K; k += 4) {
                float4 xv = *(const float4*)&xr[wid][k];
                a0 = fmaf(xv.x, Wl[(k + 0) * FD + lane], a0);
                a1 = fmaf(xv.y, Wl[(k + 1) * FD + lane], a1);
                a2 = fmaf(xv.z, Wl[(k + 2) * FD + lane], a2);
                a3 = fmaf(xv.w, Wl[(k + 3) * FD + lane], a3);
            }
            Y[(size_t)r * FD + lane] = (a0 + a1) + (a2 + a3);
        }
        __syncthreads();
    }
}

// ---------------- edge aggregation (CSR by dst, no atomics) ----------------
// out[d] = dinv[d] * sum_{e: dst=d} dinv[src_e] * X[src_e] + dinv[d]^2 * X[d] + bias

__global__ __launch_bounds__(256) void k_agg(const float* __restrict__ X,
                                             const int* __restrict__ col,
                                             const int* __restrict__ rowptr,
                                             const float* __restrict__ dinv,
                                             const float* __restrict__ bias,
                                             float* __restrict__ out, int n) {
    int t = blockIdx.x * 256 + threadIdx.x;
    int node = t >> 4;
    int lane = t & 15;
    if (node >= n) return;
    int beg = rowptr[node], end = rowptr[node + 1];
    float4 acc = make_float4(0.f, 0.f, 0.f, 0.f);
    for (int e = beg; e < end; ++e) {
        int s = col[e];
        float w = dinv[s];
        float4 v = ((const float4*)(X + (size_t)s * FD))[lane];
        acc.x = fmaf(w, v.x, acc.x);
        acc.y = fmaf(w, v.y, acc.y);
        acc.z = fmaf(w, v.z, acc.z);
        acc.w = fmaf(w, v.w, acc.w);
    }
    float di = dinv[node];
    float4 sv = ((const float4*)(X + (size_t)node * FD))[lane];
    float4 b  = ((const float4*)bias)[lane];
    float4 o;
    o.x = fmaf(di, acc.x, fmaf(di * di, sv.x, b.x));
    o.y = fmaf(di, acc.y, fmaf(di * di, sv.y, b.y));
    o.z = fmaf(di, acc.z, fmaf(di * di, sv.z, b.z));
    o.w = fmaf(di, acc.w, fmaf(di * di, sv.w, b.w));
    ((float4*)(out + (size_t)node * FD))[lane] = o;
}

// ---------------- launch ----------------

extern "C" void kernel_launch(void* const* d_in, const int* in_sizes, int n_in,
                              void* d_out, int out_size, void* d_ws, size_t ws_size,
                              hipStream_t stream) {
    const float* emb = (const float*)d_in[0];
    const float* W1  = (const float*)d_in[1];
    const float* b1  = (const float*)d_in[2];
    const float* W2  = (const float*)d_in[3];
    const float* b2  = (const float*)d_in[4];
    const int*   src = (const int*)d_in[5];
    const int*   dst = (const int*)d_in[6];

    const int D = 128;
    const int N = in_sizes[0] / D;
    const int E = in_sizes[5];
    float* out = (float*)d_out;

    // workspace layout (all 4B types; d_ws is 256B-aligned)
    float* A        = (float*)d_ws;                 // N*FD f32 scratch (xW1, then hW2)
    int*   col      = (int*)(A + (size_t)N * FD);   // E   CSR column (src ids)
    int*   deg      = col + E;                      // N
    int*   cursor   = deg + N;                      // N   (adjacent to deg for one memset)
    int*   rowptr   = cursor + N;                   // N+1
    int*   partials = rowptr + N + 1;               // <=1024
    float* dinv     = (float*)(partials + 1024);    // N

    hipMemsetAsync(deg, 0, sizeof(int) * (size_t)(2 * N), stream);  // deg + cursor

    const int npp   = (N + P - 1) / P;   // nodes per partition
    const int GPART = 2048;              // 256 blocks per partition

    int npart = (N + 1023) >> 10;
    k_deg_part<<<GPART, 256, 0, stream>>>(dst, E, deg, npp, N);
    k_scan_block<<<npart, 1024, 0, stream>>>(deg, N, rowptr, partials);
    k_scan_block<<<1, 1024, 0, stream>>>(partials, npart, partials, nullptr);
    k_fix<<<(N + 255) / 256, 256, 0, stream>>>(rowptr, partials, deg, dinv, N, E);
    k_scatter_part<<<GPART, 256, 0, stream>>>(src, dst, E, rowptr, cursor, col, npp, N);

    // layer 1: A = emb @ W1 ; out(h) = aggregate(A) + b1   (ReLU deferred to GEMM-2 load)
    k_gemm<128, false><<<4096, 256, 0, stream>>>(emb, W1, A, N);
    k_agg<<<(N * 16 + 255) / 256, 256, 0, stream>>>(A, col, rowptr, dinv, b1, out, N);
    // layer 2: A = relu(h) @ W2 ; out = aggregate(A) + b2
    k_gemm<64, true><<<4096, 256, 0, stream>>>(out, W2, A, N);
    k_agg<<<(N * 16 + 255) / 256, 256, 0, stream>>>(A, col, rowptr, dinv, b2, out, N);
}

// Round 3
// 351.466 us; speedup vs baseline: 1.2808x; 1.1926x over previous
//
#include <hip/hip_runtime.h>

constexpr int FD = 64;   // feature dim of both GCN layers (H == O == 64)
constexpr int P  = 8;    // dst-range partitions (== #XCDs; blockIdx%8 ~ XCD)

// ---------------- CSR build (XCD-partitioned to kill write amplification) ----

__global__ __launch_bounds__(256) void k_deg_part(const int* __restrict__ dst, int E,
                                                  int* __restrict__ deg,
                                                  int npp, int N) {
    int p  = blockIdx.x & (P - 1);
    int j  = blockIdx.x >> 3;
    int B  = gridDim.x >> 3;
    int lo = p * npp;
    int hi = min(lo + npp, N);
    for (int e = j * 256 + threadIdx.x; e < E; e += B * 256) {
        int d = dst[e];
        if (d >= lo && d < hi) atomicAdd(&deg[d], 1);
    }
}

__global__ __launch_bounds__(256) void k_scatter_part(const int* __restrict__ src,
                                                      const int* __restrict__ dst, int E,
                                                      const int* __restrict__ rowptr,
                                                      int* __restrict__ cursor,
                                                      int* __restrict__ col,
                                                      int npp, int N) {
    int p  = blockIdx.x & (P - 1);
    int j  = blockIdx.x >> 3;
    int B  = gridDim.x >> 3;
    int lo = p * npp;
    int hi = min(lo + npp, N);
    for (int e = j * 256 + threadIdx.x; e < E; e += B * 256) {
        int d = dst[e];
        if (d >= lo && d < hi) {
            int pos = rowptr[d] + atomicAdd(&cursor[d], 1);
            col[pos] = src[e];
        }
    }
}

// Block-level exclusive scan of 1024 elements (16 waves of 64).
__global__ __launch_bounds__(1024) void k_scan_block(const int* __restrict__ in, int n,
                                                     int* __restrict__ out,
                                                     int* __restrict__ partials) {
    __shared__ int wsum[16];
    int gid  = blockIdx.x * 1024 + threadIdx.x;
    int lane = threadIdx.x & 63, wid = threadIdx.x >> 6;
    int v = (gid < n) ? in[gid] : 0;
    int x = v;
#pragma unroll
    for (int o = 1; o < 64; o <<= 1) { int y = __shfl_up(x, o, 64); if (lane >= o) x += y; }
    if (lane == 63) wsum[wid] = x;
    __syncthreads();
    if (wid == 0) {
        int s = (lane < 16) ? wsum[lane] : 0;
#pragma unroll
        for (int o = 1; o < 16; o <<= 1) { int y = __shfl_up(s, o, 64); if (lane >= o) s += y; }
        if (lane < 16) wsum[lane] = s;   // inclusive scan of wave sums
    }
    __syncthreads();
    int base = (wid > 0) ? wsum[wid - 1] : 0;
    int incl = base + x;
    if (gid < n) out[gid] = incl - v;                       // exclusive
    if (partials && threadIdx.x == 1023) partials[blockIdx.x] = incl;  // block total
}

__global__ void k_fix(int* __restrict__ rowptr, const int* __restrict__ partials,
                      const int* __restrict__ deg, float* __restrict__ dinv, int n, int E) {
    int i = blockIdx.x * blockDim.x + threadIdx.x;
    if (i < n) {
        rowptr[i] += partials[i >> 10];
        dinv[i] = rsqrtf((float)(deg[i] + 1));   // +1 = self-loop
    }
    if (i == 0) rowptr[n] = E;
}

// ---------------- register-tiled GEMM: Y[n,64] = act(X)[n,K] @ W[K,64] -------
// Block: 256 threads = 32 row-groups x 8 col-groups; thread tile 8x8.
// Block tile: 256 rows x 64 cols. A staged in K-panels of 32, transposed
// As[k][m] (stride 260: float4-aligned, 4-way instead of 8-way write conflict).
// W (Bs) fully LDS-resident. 4 ds_read_b128 per 64 FMAs -> ~1 B LDS per FMA.

template <int K, bool RELU>
__global__ __launch_bounds__(256) void k_gemm(const float* __restrict__ X,
                                              const float* __restrict__ W,
                                              float* __restrict__ Y, int n) {
    constexpr int ASTR = 260;
    __shared__ __align__(16) float Bs[K * FD];
    __shared__ __align__(16) float As[32 * ASTR];
    for (int i = threadIdx.x; i < K * FD / 4; i += 256)
        ((float4*)Bs)[i] = ((const float4*)W)[i];

    const int rt   = threadIdx.x >> 3;  // 0..31 (row group)
    const int ct   = threadIdx.x & 7;   // 0..7  (col group)
    const int row0 = blockIdx.x * 256;
    float acc[8][8] = {};

    for (int kp = 0; kp < K; kp += 32) {
        __syncthreads();   // Bs ready (iter 0) / previous As reads done
        // stage A panel transposed: thread (mq, q) loads X[row0+mq+32p][kp+4q..+3]
        const int mq = threadIdx.x >> 3;
        const int q  = threadIdx.x & 7;
        float4 tv[8];
#pragma unroll
        for (int pass = 0; pass < 8; ++pass) {
            int grow = row0 + mq + pass * 32;
            float4 v = make_float4(0.f, 0.f, 0.f, 0.f);
            if (grow < n) {
                v = *(const float4*)&X[(size_t)grow * K + kp + q * 4];
                if (RELU) {
                    v.x = fmaxf(v.x, 0.f); v.y = fmaxf(v.y, 0.f);
                    v.z = fmaxf(v.z, 0.f); v.w = fmaxf(v.w, 0.f);
                }
            }
            tv[pass] = v;
        }
#pragma unroll
        for (int pass = 0; pass < 8; ++pass) {
            int m = mq + pass * 32;
            As[(q * 4 + 0) * ASTR + m] = tv[pass].x;
            As[(q * 4 + 1) * ASTR + m] = tv[pass].y;
            As[(q * 4 + 2) * ASTR + m] = tv[pass].z;
            As[(q * 4 + 3) * ASTR + m] = tv[pass].w;
        }
        __syncthreads();
#pragma unroll 8
        for (int k = 0; k < 32; ++k) {
            float4 a0 = *(const float4*)&As[k * ASTR + rt * 8];
            float4 a1 = *(const float4*)&As[k * ASTR + rt * 8 + 4];
            float4 b0 = *(const float4*)&Bs[(kp + k) * FD + ct * 8];
            float4 b1 = *(const float4*)&Bs[(kp + k) * FD + ct * 8 + 4];
            float af[8] = {a0.x, a0.y, a0.z, a0.w, a1.x, a1.y, a1.z, a1.w};
            float bf[8] = {b0.x, b0.y, b0.z, b0.w, b1.x, b1.y, b1.z, b1.w};
#pragma unroll
            for (int i = 0; i < 8; ++i)
#pragma unroll
                for (int j = 0; j < 8; ++j)
                    acc[i][j] = fmaf(af[i], bf[j], acc[i][j]);
        }
    }
#pragma unroll
    for (int i = 0; i < 8; ++i) {
        int r = row0 + rt * 8 + i;
        if (r < n) {
            float4 o0 = make_float4(acc[i][0], acc[i][1], acc[i][2], acc[i][3]);
            float4 o1 = make_float4(acc[i][4], acc[i][5], acc[i][6], acc[i][7]);
            *(float4*)&Y[(size_t)r * FD + ct * 8]     = o0;
            *(float4*)&Y[(size_t)r * FD + ct * 8 + 4] = o1;
        }
    }
}

// ---------------- edge aggregation (CSR by dst, no atomics) ----------------
// out[d] = dinv[d] * sum_{e: dst=d} dinv[src_e] * X[src_e] + dinv[d]^2 * X[d] + bias

__global__ __launch_bounds__(256) void k_agg(const float* __restrict__ X,
                                             const int* __restrict__ col,
                                             const int* __restrict__ rowptr,
                                             const float* __restrict__ dinv,
                                             const float* __restrict__ bias,
                                             float* __restrict__ out, int n) {
    int t = blockIdx.x * 256 + threadIdx.x;
    int node = t >> 4;
    int lane = t & 15;
    if (node >= n) return;
    int beg = rowptr[node], end = rowptr[node + 1];
    float4 acc = make_float4(0.f, 0.f, 0.f, 0.f);
    for (int e = beg; e < end; ++e) {
        int s = col[e];
        float w = dinv[s];
        float4 v = ((const float4*)(X + (size_t)s * FD))[lane];
        acc.x = fmaf(w, v.x, acc.x);
        acc.y = fmaf(w, v.y, acc.y);
        acc.z = fmaf(w, v.z, acc.z);
        acc.w = fmaf(w, v.w, acc.w);
    }
    float di = dinv[node];
    float4 sv = ((const float4*)(X + (size_t)node * FD))[lane];
    float4 b  = ((const float4*)bias)[lane];
    float4 o;
    o.x = fmaf(di, acc.x, fmaf(di * di, sv.x, b.x));
    o.y = fmaf(di, acc.y, fmaf(di * di, sv.y, b.y));
    o.z = fmaf(di, acc.z, fmaf(di * di, sv.z, b.z));
    o.w = fmaf(di, acc.w, fmaf(di * di, sv.w, b.w));
    ((float4*)(out + (size_t)node * FD))[lane] = o;
}

// ---------------- launch ----------------

extern "C" void kernel_launch(void* const* d_in, const int* in_sizes, int n_in,
                              void* d_out, int out_size, void* d_ws, size_t ws_size,
                              hipStream_t stream) {
    const float* emb = (const float*)d_in[0];
    const float* W1  = (const float*)d_in[1];
    const float* b1  = (const float*)d_in[2];
    const float* W2  = (const float*)d_in[3];
    const float* b2  = (const float*)d_in[4];
    const int*   src = (const int*)d_in[5];
    const int*   dst = (const int*)d_in[6];

    const int D = 128;
    const int N = in_sizes[0] / D;
    const int E = in_sizes[5];
    float* out = (float*)d_out;

    // workspace layout (all 4B types; d_ws is 256B-aligned)
    float* A        = (float*)d_ws;                 // N*FD f32 scratch (xW1, then hW2)
    int*   col      = (int*)(A + (size_t)N * FD);   // E   CSR column (src ids)
    int*   deg      = col + E;                      // N
    int*   cursor   = deg + N;                      // N   (adjacent to deg for one memset)
    int*   rowptr   = cursor + N;                   // N+1
    int*   partials = rowptr + N + 1;               // <=1024
    float* dinv     = (float*)(partials + 1024);    // N

    hipMemsetAsync(deg, 0, sizeof(int) * (size_t)(2 * N), stream);  // deg + cursor

    const int npp   = (N + P - 1) / P;   // nodes per partition
    const int GPART = 2048;              // 256 blocks per partition

    int npart = (N + 1023) >> 10;
    k_deg_part<<<GPART, 256, 0, stream>>>(dst, E, deg, npp, N);
    k_scan_block<<<npart, 1024, 0, stream>>>(deg, N, rowptr, partials);
    k_scan_block<<<1, 1024, 0, stream>>>(partials, npart, partials, nullptr);
    k_fix<<<(N + 255) / 256, 256, 0, stream>>>(rowptr, partials, deg, dinv, N, E);
    k_scatter_part<<<GPART, 256, 0, stream>>>(src, dst, E, rowptr, cursor, col, npp, N);

    int gblocks = (N + 255) / 256;
    // layer 1: A = emb @ W1 ; out(h) = aggregate(A) + b1   (ReLU deferred to GEMM-2 load)
    k_gemm<128, false><<<gblocks, 256, 0, stream>>>(emb, W1, A, N);
    k_agg<<<(N * 16 + 255) / 256, 256, 0, stream>>>(A, col, rowptr, dinv, b1, out, N);
    // layer 2: A = relu(h) @ W2 ; out = aggregate(A) + b2
    k_gemm<64, true><<<gblocks, 256, 0, stream>>>(out, W2, A, N);
    k_agg<<<(N * 16 + 255) / 256, 256, 0, stream>>>(A, col, rowptr, dinv, b2, out, N);
}